// Round 2
// baseline (8737.712 us; speedup 1.0000x reference)
//
#include <hip/hip_runtime.h>
#include <cstdint>
#include <cstddef>

// Problem constants (LSTM_62173946577315): T=256, B=128, E=1024, H=1024.
#define Tn 256
#define Bn 128
#define En 1024
#define Hn 1024
#define NG 4096   // 4*H gate rows, order [g,i,f,o]

typedef __bf16 bf16;
typedef __bf16 bf16x8 __attribute__((ext_vector_type(8)));
typedef __bf16 bf16x4 __attribute__((ext_vector_type(4)));
typedef float  f32x4  __attribute__((ext_vector_type(4)));
typedef float  f32x2  __attribute__((ext_vector_type(2)));

typedef __attribute__((address_space(1))) void gvoid;
typedef __attribute__((address_space(3))) void lvoid;

__device__ __forceinline__ float sigmoidf_(float x) {
  return 1.0f / (1.0f + __expf(-x));
}

// Unpack bf16 element j (0=low,1=high) of a u32 pair to float. j is
// compile-time under #pragma unroll.
__device__ __forceinline__ float bf16_of(unsigned w, int j) {
  unsigned short s = (j == 0) ? (unsigned short)(w & 0xffffu)
                              : (unsigned short)(w >> 16);
  return (float)__builtin_bit_cast(bf16, s);
}

// ---------------------------------------------------------------------------
// prep_w: split W_* (H x (E+H)) fp32 into Wx[4][H][E], Wh[4][H][H] bf16
// (row-major over k) and concatenate biases into bias[4096] fp32.
// ---------------------------------------------------------------------------
__global__ __launch_bounds__(256) void prep_w(
    const float* __restrict__ Wg, const float* __restrict__ Wi,
    const float* __restrict__ Wf, const float* __restrict__ Wo,
    const float* __restrict__ bg, const float* __restrict__ bi,
    const float* __restrict__ bff, const float* __restrict__ bo,
    bf16* __restrict__ Wx, bf16* __restrict__ Wh, float* __restrict__ bias)
{
  int idx = blockIdx.x * 256 + threadIdx.x;   // 0 .. 4*1024*1024-1
  int g = idx >> 20;
  int r = idx & 0xFFFFF;                      // u*1024 + k
  int u = r >> 10;
  int k = r & 1023;
  const float* Ws = (g == 0) ? Wg : (g == 1) ? Wi : (g == 2) ? Wf : Wo;
  size_t src = (size_t)u * (En + Hn) + k;
  Wx[idx] = (bf16)Ws[src];        // x-part: cols [0, E)
  Wh[idx] = (bf16)Ws[src + En];   // h-part: cols [E, E+H)
  if (idx < NG) {
    int gg = idx >> 10, uu = idx & 1023;
    const float* bs = (gg == 0) ? bg : (gg == 1) ? bi : (gg == 2) ? bff : bo;
    bias[idx] = bs[uu];
  }
}

// ---------------------------------------------------------------------------
// conv_x: embeds fp32 (T*B*E) -> bf16, vectorized x4.
// ---------------------------------------------------------------------------
__global__ __launch_bounds__(256) void conv_x(const float* __restrict__ X,
                                              bf16* __restrict__ Xb)
{
  int idx = blockIdx.x * 256 + threadIdx.x;   // per float4
  f32x4 v = ((const f32x4*)X)[idx];
  bf16x4 o;
  o[0] = (bf16)v[0]; o[1] = (bf16)v[1]; o[2] = (bf16)v[2]; o[3] = (bf16)v[3];
  ((bf16x4*)Xb)[idx] = o;
}

// ---------------------------------------------------------------------------
// zx_gemm: ZX[m][n] = sum_k Xb[m+128][k] * Wx[n][k] + bias[n], m = (t-1)*128+b
// for t in [1,256). M=32640, N=4096, K=1024. bf16 in, fp32 accum, bf16 out.
// ---------------------------------------------------------------------------
__global__ __launch_bounds__(256) void zx_gemm(
    const bf16* __restrict__ Xb, const bf16* __restrict__ Wx,
    const float* __restrict__ bias, bf16* __restrict__ zx)
{
  const int tid  = threadIdx.x;
  const int lane = tid & 63;
  const int wave = tid >> 6;
  const int wm = wave >> 1, wn = wave & 1;
  const int l15 = lane & 15, lq = lane >> 4;
  const int n0 = blockIdx.x * 64 + wn * 32;
  const int m0 = blockIdx.y * 64 + wm * 32;

  const f32x4 zero4 = {0.f, 0.f, 0.f, 0.f};
  f32x4 acc[2][2] = {{zero4, zero4}, {zero4, zero4}};

  const bf16* Ap = Xb + ((size_t)(128 + m0 + l15)) * En + lq * 8;
  const bf16* Bp = Wx + ((size_t)(n0 + l15)) * En + lq * 8;

  #pragma unroll 4
  for (int kc = 0; kc < En / 32; ++kc) {
    bf16x8 a0 = *(const bf16x8*)(Ap + kc * 32);
    bf16x8 a1 = *(const bf16x8*)(Ap + (size_t)16 * En + kc * 32);
    bf16x8 b0 = *(const bf16x8*)(Bp + kc * 32);
    bf16x8 b1 = *(const bf16x8*)(Bp + (size_t)16 * En + kc * 32);
    acc[0][0] = __builtin_amdgcn_mfma_f32_16x16x32_bf16(a0, b0, acc[0][0], 0, 0, 0);
    acc[0][1] = __builtin_amdgcn_mfma_f32_16x16x32_bf16(a0, b1, acc[0][1], 0, 0, 0);
    acc[1][0] = __builtin_amdgcn_mfma_f32_16x16x32_bf16(a1, b0, acc[1][0], 0, 0, 0);
    acc[1][1] = __builtin_amdgcn_mfma_f32_16x16x32_bf16(a1, b1, acc[1][1], 0, 0, 0);
  }

  #pragma unroll
  for (int mt = 0; mt < 2; ++mt)
    #pragma unroll
    for (int nt = 0; nt < 2; ++nt)
      #pragma unroll
      for (int i = 0; i < 4; ++i) {
        int m = m0 + mt * 16 + lq * 4 + i;   // C row = (lane>>4)*4 + reg
        int n = n0 + nt * 16 + l15;          // C col = lane&15
        zx[(size_t)m * NG + n] = (bf16)(acc[mt][nt][i] + bias[n]);
      }
}

// ---------------------------------------------------------------------------
// lstm_persist: the whole 255-step scan in ONE cooperative kernel.
// Grid 256 blocks x 256 threads (1 block/CU). Block = (unit-tile ut of 16,
// batch-quarter qb of 32 rows). Wave w = gate g, holding its Wh slice
// (16 n-rows x 1024 k) in 128 VGPRs for the whole kernel.
//
// SYNC DESIGN: the four batch-quarters are fully independent recurrence
// chains (block (ut,qb) reads/writes only h rows of its own qb), so sync is
// four independent 64-block barriers. Cross-XCD h visibility is FENCE-FREE:
// h stores are relaxed agent-scope atomic stores (HW writes through to L3,
// the coherence point), h staging loads carry sc0|sc1 (aux=0x11) so they
// bypass stale per-CU L1 / per-XCD L2 and read at L3. Flag atomics are
// RELAXED -> NO buffer_wbl2 / buffer_inv cache-wide ops in the loop.
// Ordering: the vmcnt(0) drain before each s_barrier guarantees h stores
// are acked at L3 before the flag increment is issued.
// ---------------------------------------------------------------------------
#define HS_STRIDE 1032   // 1024 + 8 bf16 pad -> 2064 B row stride

__global__ __launch_bounds__(256, 1) void lstm_persist(
    const bf16* __restrict__ Wh,    // [4][1024][1024]
    const bf16* __restrict__ zx,    // [255*128][4096] (bias folded in)
    bf16* __restrict__ hb0,         // ping [128][1024]
    bf16* __restrict__ hb1,         // pong [128][1024]
    float* __restrict__ out,        // [256][128][1024]
    unsigned int* __restrict__ bar) // [1024] zero-initialized slots: [(t-1)*4+qb]
{
  const int tid  = threadIdx.x;
  const int lane = tid & 63;
  const int g    = tid >> 6;         // wave index == gate
  const int l15  = lane & 15;
  const int lq   = lane >> 4;
  const int ut   = blockIdx.x & 63;  // unit tile (16 units)
  const int qb   = blockIdx.x >> 6;  // batch quarter (32 rows)

  __shared__ bf16  hs[32 * HS_STRIDE];   // 66,048 B
  __shared__ float zs[4][32][18];        //  9,216 B

  // --- Preload this wave's Wh slice into registers: 16 n x 1024 k ---------
  bf16x8 wfrag[32];
  {
    const bf16* wp = Wh + ((size_t)(g * Hn + ut * 16 + l15)) * Hn + lq * 8;
    #pragma unroll
    for (int ks = 0; ks < 32; ++ks)
      wfrag[ks] = *(const bf16x8*)(wp + ks * 32);
  }

  // --- Elementwise ownership: 2 ADJACENT units of one batch row -----------
  // (enables one u32 h-store, one 8B out-store, u32 zx loads)
  const int bl   = tid >> 3;          // 0..31 batch row within tile
  const int up0  = (tid & 7) << 1;    // 0,2,..,14 unit pair within tile
  const int brow = qb * 32 + bl;
  const int u0   = ut * 16 + up0;

  float creg[2] = {0.f, 0.f};        // c for units u0, u0+1 of row brow
  const f32x4 zero4 = {0.f, 0.f, 0.f, 0.f};

  for (int t = 1; t < Tn; ++t) {
    const bf16* hin  = ((t - 1) & 1) ? hb1 : hb0;
    bf16*       hout = (t & 1) ? hb1 : hb0;

    // --- zx prefetch: independent of h; latency hides under staging+MFMA --
    unsigned zxw[4];
    {
      const bf16* zrow = zx + ((size_t)(t - 1) * Bn + brow) * NG + u0;
      #pragma unroll
      for (int gg = 0; gg < 4; ++gg)
        zxw[gg] = *(const unsigned*)(zrow + gg * Hn);
    }

    // --- Stage h(t-1) block tile (32 rows x 1024 k) into LDS -------------
    // 64 half-rows of 1024 B; wave g handles half-rows [g*16, g*16+16).
    // aux=0x11 (sc0|sc1): bypass L1+L2, read coherently at L3.
    #pragma unroll
    for (int j = 0; j < 16; ++j) {
      int rh   = g * 16 + j;
      int row  = rh >> 1;
      int half = rh & 1;
      const bf16* src = hin + ((size_t)(qb * 32 + row)) * Hn + half * 512 + lane * 8;
      bf16* dst = &hs[row * HS_STRIDE + half * 512];
      __builtin_amdgcn_global_load_lds((const gvoid*)src, (lvoid*)dst, 16, 0, 0x11);
    }
    __syncthreads();   // staging complete (vmcnt(0) + barrier); zx in regs too

    // --- z partial = h_tile @ Wh_g^T : 2 mt x 32 ks MFMAs ----------------
    f32x4 acc[2] = {zero4, zero4};
    #pragma unroll
    for (int ks = 0; ks < 32; ++ks) {
      bf16x8 a0 = *(const bf16x8*)&hs[(l15) * HS_STRIDE + ks * 32 + lq * 8];
      bf16x8 a1 = *(const bf16x8*)&hs[(16 + l15) * HS_STRIDE + ks * 32 + lq * 8];
      acc[0] = __builtin_amdgcn_mfma_f32_16x16x32_bf16(a0, wfrag[ks], acc[0], 0, 0, 0);
      acc[1] = __builtin_amdgcn_mfma_f32_16x16x32_bf16(a1, wfrag[ks], acc[1], 0, 0, 0);
    }

    // --- Gate exchange through LDS ---------------------------------------
    #pragma unroll
    for (int mt = 0; mt < 2; ++mt)
      #pragma unroll
      for (int i = 0; i < 4; ++i)
        zs[g][mt * 16 + lq * 4 + i][l15] = acc[mt][i];
    __syncthreads();

    // --- Fused elementwise: 2 adjacent cells per thread ------------------
    {
      float hv[2];
      unsigned short hp[2];
      #pragma unroll
      for (int j = 0; j < 2; ++j) {
        int ul = up0 + j;
        float zg = zs[0][bl][ul] + bf16_of(zxw[0], j);
        float zi = zs[1][bl][ul] + bf16_of(zxw[1], j);
        float zf = zs[2][bl][ul] + bf16_of(zxw[2], j);
        float zo = zs[3][bl][ul] + bf16_of(zxw[3], j);
        float gv = tanhf(zg);
        float iv = sigmoidf_(zi);
        float fv = sigmoidf_(zf);
        float ov = sigmoidf_(zo);
        float cv = fv * creg[j] + iv * gv;
        creg[j] = cv;
        hv[j] = ov * tanhf(cv);
        hp[j] = __builtin_bit_cast(unsigned short, (bf16)hv[j]);
      }
      size_t off = (size_t)brow * Hn + u0;
      // h: relaxed agent-scope atomic store -> write-through to L3 (no fence)
      unsigned hpack = (unsigned)hp[0] | ((unsigned)hp[1] << 16);
      __hip_atomic_store((unsigned int*)(hout + off), hpack,
                         __ATOMIC_RELAXED, __HIP_MEMORY_SCOPE_AGENT);
      // out: nontemporal 8B store, don't dirty L2
      f32x2 ov2 = {hv[0], hv[1]};
      __builtin_nontemporal_store(ov2, (f32x2*)(out + (size_t)t * Bn * Hn + off));
    }

    // --- Per-quarter barrier: 64 blocks, fresh slot per step -------------
    if (t < Tn - 1) {
      asm volatile("s_waitcnt vmcnt(0)" ::: "memory");  // h stores acked @L3
      __syncthreads();
      if (tid == 0) {
        unsigned slot = (((unsigned)(t - 1)) << 2) | (unsigned)qb;
        unsigned old = __hip_atomic_fetch_add(&bar[slot], 1u, __ATOMIC_RELAXED,
                                              __HIP_MEMORY_SCOPE_AGENT);
        if (old != 63u) {   // last arriver skips the spin entirely
          while (__hip_atomic_load(&bar[slot], __ATOMIC_RELAXED,
                                   __HIP_MEMORY_SCOPE_AGENT) < 64u) {
            __builtin_amdgcn_s_sleep(2);
          }
        }
      }
      __syncthreads();
    }
  }
}

// ---------------------------------------------------------------------------
// kernel_launch
// ---------------------------------------------------------------------------
extern "C" void kernel_launch(void* const* d_in, const int* in_sizes, int n_in,
                              void* d_out, int out_size, void* d_ws, size_t ws_size,
                              hipStream_t stream) {
  const float* embeds = (const float*)d_in[0];
  const float* Wg = (const float*)d_in[1];
  const float* Wi = (const float*)d_in[2];
  const float* Wf = (const float*)d_in[3];
  const float* Wo = (const float*)d_in[4];
  const float* bg = (const float*)d_in[5];
  const float* bi = (const float*)d_in[6];
  const float* bff = (const float*)d_in[7];
  const float* bo = (const float*)d_in[8];
  float* out = (float*)d_out;

  // Workspace carve (bytes; all >=16B-aligned):
  //   Wx bf16  [4096][1024]          @ 0          (8,388,608)  [dead after
  //        zx_gemm; first 4 KB reused as the 1024 barrier slots]
  //   Wh bf16  [4096][1024]          @ 8388608    (8,388,608)
  //   bias f32 [4096]                @ 16777216   (16,384)
  //   Xb bf16  [256][128][1024]      @ 16793600   (67,108,864)
  //   zx bf16  [32640][4096]         @ 83902464   (267,386,880)
  //   h0 bf16  [128][1024]           @ 351289344  (262,144)
  //   h1 bf16  [128][1024]           @ 351551488  (262,144)
  char* ws = (char*)d_ws;
  bf16*  Wx   = (bf16*)(ws + 0);
  bf16*  Wh   = (bf16*)(ws + 8388608);
  float* bias = (float*)(ws + 16777216);
  bf16*  Xb   = (bf16*)(ws + 16793600);
  bf16*  zx   = (bf16*)(ws + 83902464);
  bf16*  h0b  = (bf16*)(ws + 351289344);
  bf16*  h1b  = (bf16*)(ws + 351551488);
  unsigned int* bar = (unsigned int*)(ws + 0);   // aliases dead Wx region

  // out[0] = h0 = zeros; zero h ping buffer.
  hipMemsetAsync(out, 0, (size_t)Bn * Hn * sizeof(float), stream);
  hipMemsetAsync(h0b, 0, (size_t)Bn * Hn * sizeof(bf16), stream);

  prep_w<<<16384, 256, 0, stream>>>(Wg, Wi, Wf, Wo, bg, bi, bff, bo, Wx, Wh, bias);
  conv_x<<<32768, 256, 0, stream>>>(embeds, Xb);
  zx_gemm<<<dim3(64, 510), 256, 0, stream>>>(Xb, Wx, bias, zx);

  // Wx is dead now; zero the barrier slots living at its base (stream-ordered
  // after zx_gemm, before the cooperative launch).
  hipMemsetAsync(bar, 0, 1024 * sizeof(unsigned int), stream);

  void* args[] = {(void*)&Wh, (void*)&zx, (void*)&h0b, (void*)&h1b,
                  (void*)&out, (void*)&bar};
  hipLaunchCooperativeKernel((void*)lstm_persist, dim3(256), dim3(256),
                             args, 0, stream);
}

// Round 3
// 3433.876 us; speedup vs baseline: 2.5446x; 2.5446x over previous
//
#include <hip/hip_runtime.h>
#include <cstdint>
#include <cstddef>

// Problem constants (LSTM_62173946577315): T=256, B=128, E=1024, H=1024.
#define Tn 256
#define Bn 128
#define En 1024
#define Hn 1024
#define NG 4096   // 4*H gate rows, order [g,i,f,o]

typedef __bf16 bf16;
typedef __bf16 bf16x8 __attribute__((ext_vector_type(8)));
typedef __bf16 bf16x4 __attribute__((ext_vector_type(4)));
typedef float  f32x4  __attribute__((ext_vector_type(4)));
typedef float  f32x2  __attribute__((ext_vector_type(2)));

typedef __attribute__((address_space(1))) void gvoid;
typedef __attribute__((address_space(3))) void lvoid;

__device__ __forceinline__ float sigmoidf_(float x) {
  return 1.0f / (1.0f + __expf(-x));
}

// Unpack bf16 element j (0=low,1=high) of a u32 pair to float. j is
// compile-time under #pragma unroll.
__device__ __forceinline__ float bf16_of(unsigned w, int j) {
  unsigned short s = (j == 0) ? (unsigned short)(w & 0xffffu)
                              : (unsigned short)(w >> 16);
  return (float)__builtin_bit_cast(bf16, s);
}

// ---------------------------------------------------------------------------
// prep_w: split W_* (H x (E+H)) fp32 into Wx[4][H][E], Wh[4][H][H] bf16
// (row-major over k) and concatenate biases into bias[4096] fp32.
// ---------------------------------------------------------------------------
__global__ __launch_bounds__(256) void prep_w(
    const float* __restrict__ Wg, const float* __restrict__ Wi,
    const float* __restrict__ Wf, const float* __restrict__ Wo,
    const float* __restrict__ bg, const float* __restrict__ bi,
    const float* __restrict__ bff, const float* __restrict__ bo,
    bf16* __restrict__ Wx, bf16* __restrict__ Wh, float* __restrict__ bias)
{
  int idx = blockIdx.x * 256 + threadIdx.x;   // 0 .. 4*1024*1024-1
  int g = idx >> 20;
  int r = idx & 0xFFFFF;                      // u*1024 + k
  int u = r >> 10;
  int k = r & 1023;
  const float* Ws = (g == 0) ? Wg : (g == 1) ? Wi : (g == 2) ? Wf : Wo;
  size_t src = (size_t)u * (En + Hn) + k;
  Wx[idx] = (bf16)Ws[src];        // x-part: cols [0, E)
  Wh[idx] = (bf16)Ws[src + En];   // h-part: cols [E, E+H)
  if (idx < NG) {
    int gg = idx >> 10, uu = idx & 1023;
    const float* bs = (gg == 0) ? bg : (gg == 1) ? bi : (gg == 2) ? bff : bo;
    bias[idx] = bs[uu];
  }
}

// ---------------------------------------------------------------------------
// conv_x: embeds fp32 (T*B*E) -> bf16, vectorized x4.
// ---------------------------------------------------------------------------
__global__ __launch_bounds__(256) void conv_x(const float* __restrict__ X,
                                              bf16* __restrict__ Xb)
{
  int idx = blockIdx.x * 256 + threadIdx.x;   // per float4
  f32x4 v = ((const f32x4*)X)[idx];
  bf16x4 o;
  o[0] = (bf16)v[0]; o[1] = (bf16)v[1]; o[2] = (bf16)v[2]; o[3] = (bf16)v[3];
  ((bf16x4*)Xb)[idx] = o;
}

// ---------------------------------------------------------------------------
// zx_gemm: ZX[m][n] = sum_k Xb[m+128][k] * Wx[n][k] + bias[n], m = (t-1)*128+b
// for t in [1,256). M=32640, N=4096, K=1024. bf16 in, fp32 accum, bf16 out.
// ---------------------------------------------------------------------------
__global__ __launch_bounds__(256) void zx_gemm(
    const bf16* __restrict__ Xb, const bf16* __restrict__ Wx,
    const float* __restrict__ bias, bf16* __restrict__ zx)
{
  const int tid  = threadIdx.x;
  const int lane = tid & 63;
  const int wave = tid >> 6;
  const int wm = wave >> 1, wn = wave & 1;
  const int l15 = lane & 15, lq = lane >> 4;
  const int n0 = blockIdx.x * 64 + wn * 32;
  const int m0 = blockIdx.y * 64 + wm * 32;

  const f32x4 zero4 = {0.f, 0.f, 0.f, 0.f};
  f32x4 acc[2][2] = {{zero4, zero4}, {zero4, zero4}};

  const bf16* Ap = Xb + ((size_t)(128 + m0 + l15)) * En + lq * 8;
  const bf16* Bp = Wx + ((size_t)(n0 + l15)) * En + lq * 8;

  #pragma unroll 4
  for (int kc = 0; kc < En / 32; ++kc) {
    bf16x8 a0 = *(const bf16x8*)(Ap + kc * 32);
    bf16x8 a1 = *(const bf16x8*)(Ap + (size_t)16 * En + kc * 32);
    bf16x8 b0 = *(const bf16x8*)(Bp + kc * 32);
    bf16x8 b1 = *(const bf16x8*)(Bp + (size_t)16 * En + kc * 32);
    acc[0][0] = __builtin_amdgcn_mfma_f32_16x16x32_bf16(a0, b0, acc[0][0], 0, 0, 0);
    acc[0][1] = __builtin_amdgcn_mfma_f32_16x16x32_bf16(a0, b1, acc[0][1], 0, 0, 0);
    acc[1][0] = __builtin_amdgcn_mfma_f32_16x16x32_bf16(a1, b0, acc[1][0], 0, 0, 0);
    acc[1][1] = __builtin_amdgcn_mfma_f32_16x16x32_bf16(a1, b1, acc[1][1], 0, 0, 0);
  }

  #pragma unroll
  for (int mt = 0; mt < 2; ++mt)
    #pragma unroll
    for (int nt = 0; nt < 2; ++nt)
      #pragma unroll
      for (int i = 0; i < 4; ++i) {
        int m = m0 + mt * 16 + lq * 4 + i;   // C row = (lane>>4)*4 + reg
        int n = n0 + nt * 16 + l15;          // C col = lane&15
        zx[(size_t)m * NG + n] = (bf16)(acc[mt][nt][i] + bias[n]);
      }
}

// ---------------------------------------------------------------------------
// lstm_persist: the whole 255-step scan in ONE cooperative kernel.
// Grid 256 blocks x 256 threads (1 block/CU). Block = (unit-tile ut of 16,
// batch-quarter qb of 32 rows). Wave w = gate g, holding its Wh slice
// (16 n-rows x 1024 k) in 128 VGPRs for the whole kernel.
//
// SYNC: write-once dataflow flags, NO centralized barrier.
//   Producer (end of step t): h stores are relaxed agent-scope atomic u32
//   stores (write-through to L3, the cross-XCD coherence point); per-wave
//   vmcnt(0) drain + block barrier; then tid 0 sets flag[t][qb][ut] with a
//   relaxed agent-scope store. Flag in L3 strictly after h data in L3.
//   Consumer (start of step t): all 4 waves poll the 64 flags of
//   (t-1, qb) with ONE 64-lane load + __ballot until all set, then stage h
//   via global_load_lds aux=0x11 (sc0|sc1: bypass L1/L2, read at L3).
//   No fetch_add contention, no arrive/release phases, no slot reuse.
//   WAR safety of the h ping-pong is inductive: block j stores h(t+1) only
//   after seeing all flags(t); flag_m(t) implies m finished READING h(t-1);
//   h(t+1) overwrites exactly h(t-1)'s buffer. Deadlock-free: flags are
//   monotonic write-once; t=1 waits on nothing.
// ---------------------------------------------------------------------------
#define HS_STRIDE 1032   // 1024 + 8 bf16 pad -> 2064 B row stride

__global__ __launch_bounds__(256, 1) void lstm_persist(
    const bf16* __restrict__ Wh,    // [4][1024][1024]
    const bf16* __restrict__ zx,    // [255*128][4096] (bias folded in)
    bf16* __restrict__ hb0,         // ping [128][1024]
    bf16* __restrict__ hb1,         // pong [128][1024]
    float* __restrict__ out,        // [256][128][1024]
    unsigned int* __restrict__ flags) // [256][4][64] zero-init: [t][qb][ut]
{
  const int tid  = threadIdx.x;
  const int lane = tid & 63;
  const int g    = tid >> 6;         // wave index == gate
  const int l15  = lane & 15;
  const int lq   = lane >> 4;
  const int ut   = blockIdx.x & 63;  // unit tile (16 units)
  const int qb   = blockIdx.x >> 6;  // batch quarter (32 rows)

  __shared__ bf16  hs[32 * HS_STRIDE];   // 66,048 B
  __shared__ float zs[4][32][18];        //  9,216 B

  // --- Preload this wave's Wh slice into registers: 16 n x 1024 k ---------
  bf16x8 wfrag[32];
  {
    const bf16* wp = Wh + ((size_t)(g * Hn + ut * 16 + l15)) * Hn + lq * 8;
    #pragma unroll
    for (int ks = 0; ks < 32; ++ks)
      wfrag[ks] = *(const bf16x8*)(wp + ks * 32);
  }

  // --- Elementwise ownership: 2 ADJACENT units of one batch row -----------
  const int bl   = tid >> 3;          // 0..31 batch row within tile
  const int up0  = (tid & 7) << 1;    // 0,2,..,14 unit pair within tile
  const int brow = qb * 32 + bl;
  const int u0   = ut * 16 + up0;

  float creg[2] = {0.f, 0.f};        // c for units u0, u0+1 of row brow
  const f32x4 zero4 = {0.f, 0.f, 0.f, 0.f};

  for (int t = 1; t < Tn; ++t) {
    const bf16* hin  = ((t - 1) & 1) ? hb1 : hb0;
    bf16*       hout = (t & 1) ? hb1 : hb0;

    // --- zx prefetch: independent of h; issued before the flag wait ------
    unsigned zxw[4];
    {
      const bf16* zrow = zx + ((size_t)(t - 1) * Bn + brow) * NG + u0;
      #pragma unroll
      for (int gg = 0; gg < 4; ++gg)
        zxw[gg] = *(const unsigned*)(zrow + gg * Hn);
    }

    // --- Dataflow wait: all 64 tiles of h(t-1) for this quarter flagged --
    if (t > 1) {
      unsigned int* fp = flags + (((size_t)(t - 1)) * 4 + (size_t)qb) * 64;
      for (;;) {
        unsigned v = __hip_atomic_load(&fp[lane], __ATOMIC_RELAXED,
                                       __HIP_MEMORY_SCOPE_AGENT);
        if (__ballot(v != 0u) == ~0ULL) break;   // all 64 producers done
        __builtin_amdgcn_s_sleep(1);
      }
    }

    // --- Stage h(t-1) block tile (32 rows x 1024 k) into LDS -------------
    // 64 half-rows of 1024 B; wave g handles half-rows [g*16, g*16+16).
    // aux=0x11 (sc0|sc1): bypass L1+L2, read coherently at L3.
    #pragma unroll
    for (int j = 0; j < 16; ++j) {
      int rh   = g * 16 + j;
      int row  = rh >> 1;
      int half = rh & 1;
      const bf16* src = hin + ((size_t)(qb * 32 + row)) * Hn + half * 512 + lane * 8;
      bf16* dst = &hs[row * HS_STRIDE + half * 512];
      __builtin_amdgcn_global_load_lds((const gvoid*)src, (lvoid*)dst, 16, 0, 0x11);
    }
    __syncthreads();   // staging complete (vmcnt(0) + barrier)

    // --- z partial = h_tile @ Wh_g^T : 2 mt x 32 ks MFMAs ----------------
    f32x4 acc[2] = {zero4, zero4};
    #pragma unroll
    for (int ks = 0; ks < 32; ++ks) {
      bf16x8 a0 = *(const bf16x8*)&hs[(l15) * HS_STRIDE + ks * 32 + lq * 8];
      bf16x8 a1 = *(const bf16x8*)&hs[(16 + l15) * HS_STRIDE + ks * 32 + lq * 8];
      acc[0] = __builtin_amdgcn_mfma_f32_16x16x32_bf16(a0, wfrag[ks], acc[0], 0, 0, 0);
      acc[1] = __builtin_amdgcn_mfma_f32_16x16x32_bf16(a1, wfrag[ks], acc[1], 0, 0, 0);
    }

    // --- Gate exchange through LDS ---------------------------------------
    #pragma unroll
    for (int mt = 0; mt < 2; ++mt)
      #pragma unroll
      for (int i = 0; i < 4; ++i)
        zs[g][mt * 16 + lq * 4 + i][l15] = acc[mt][i];
    __syncthreads();

    // --- Fused elementwise: 2 adjacent cells per thread ------------------
    float hv0, hv1;
    {
      float hv[2];
      unsigned short hp[2];
      #pragma unroll
      for (int j = 0; j < 2; ++j) {
        int ul = up0 + j;
        float zg = zs[0][bl][ul] + bf16_of(zxw[0], j);
        float zi = zs[1][bl][ul] + bf16_of(zxw[1], j);
        float zf = zs[2][bl][ul] + bf16_of(zxw[2], j);
        float zo = zs[3][bl][ul] + bf16_of(zxw[3], j);
        float gv = tanhf(zg);
        float iv = sigmoidf_(zi);
        float fv = sigmoidf_(zf);
        float ov = sigmoidf_(zo);
        float cv = fv * creg[j] + iv * gv;
        creg[j] = cv;
        hv[j] = ov * tanhf(cv);
        hp[j] = __builtin_bit_cast(unsigned short, (bf16)hv[j]);
      }
      // h: relaxed agent-scope atomic store -> write-through to L3 (no fence)
      size_t off = (size_t)brow * Hn + u0;
      unsigned hpack = (unsigned)hp[0] | ((unsigned)hp[1] << 16);
      __hip_atomic_store((unsigned int*)(hout + off), hpack,
                         __ATOMIC_RELAXED, __HIP_MEMORY_SCOPE_AGENT);
      hv0 = hv[0]; hv1 = hv[1];
    }

    // --- Producer flag: h(t) of this tile is in L3 ------------------------
    // Each wave drains ITS h-stores (vmcnt ack = at coherence point), the
    // barrier joins all 4 waves, then one thread publishes the flag.
    asm volatile("s_waitcnt vmcnt(0)" ::: "memory");
    __syncthreads();
    if (t < Tn - 1 && tid == 0) {
      __hip_atomic_store(&flags[((size_t)t * 4 + (size_t)qb) * 64 + ut], 1u,
                         __ATOMIC_RELAXED, __HIP_MEMORY_SCOPE_AGENT);
    }

    // --- out store AFTER the flag: HBM ack latency off the critical path --
    {
      size_t off = (size_t)brow * Hn + u0;
      f32x2 ov2 = {hv0, hv1};
      __builtin_nontemporal_store(ov2, (f32x2*)(out + (size_t)t * Bn * Hn + off));
    }
  }
}

// ---------------------------------------------------------------------------
// kernel_launch
// ---------------------------------------------------------------------------
extern "C" void kernel_launch(void* const* d_in, const int* in_sizes, int n_in,
                              void* d_out, int out_size, void* d_ws, size_t ws_size,
                              hipStream_t stream) {
  const float* embeds = (const float*)d_in[0];
  const float* Wg = (const float*)d_in[1];
  const float* Wi = (const float*)d_in[2];
  const float* Wf = (const float*)d_in[3];
  const float* Wo = (const float*)d_in[4];
  const float* bg = (const float*)d_in[5];
  const float* bi = (const float*)d_in[6];
  const float* bff = (const float*)d_in[7];
  const float* bo = (const float*)d_in[8];
  float* out = (float*)d_out;

  // Workspace carve (bytes; all >=16B-aligned):
  //   Wx bf16  [4096][1024]          @ 0          (8,388,608)  [dead after
  //        zx_gemm; first 256 KB reused as the dataflow flags]
  //   Wh bf16  [4096][1024]          @ 8388608    (8,388,608)
  //   bias f32 [4096]                @ 16777216   (16,384)
  //   Xb bf16  [256][128][1024]      @ 16793600   (67,108,864)
  //   zx bf16  [32640][4096]         @ 83902464   (267,386,880)
  //   h0 bf16  [128][1024]           @ 351289344  (262,144)
  //   h1 bf16  [128][1024]           @ 351551488  (262,144)
  char* ws = (char*)d_ws;
  bf16*  Wx   = (bf16*)(ws + 0);
  bf16*  Wh   = (bf16*)(ws + 8388608);
  float* bias = (float*)(ws + 16777216);
  bf16*  Xb   = (bf16*)(ws + 16793600);
  bf16*  zx   = (bf16*)(ws + 83902464);
  bf16*  h0b  = (bf16*)(ws + 351289344);
  bf16*  h1b  = (bf16*)(ws + 351551488);
  unsigned int* flags = (unsigned int*)(ws + 0);   // aliases dead Wx region

  // out[0] = h0 = zeros; zero h ping buffer.
  hipMemsetAsync(out, 0, (size_t)Bn * Hn * sizeof(float), stream);
  hipMemsetAsync(h0b, 0, (size_t)Bn * Hn * sizeof(bf16), stream);

  prep_w<<<16384, 256, 0, stream>>>(Wg, Wi, Wf, Wo, bg, bi, bff, bo, Wx, Wh, bias);
  conv_x<<<32768, 256, 0, stream>>>(embeds, Xb);
  zx_gemm<<<dim3(64, 510), 256, 0, stream>>>(Xb, Wx, bias, zx);

  // Wx is dead now; zero the flag slots living at its base (stream-ordered
  // after zx_gemm, before the cooperative launch). [256][4][64] u32.
  hipMemsetAsync(flags, 0, (size_t)256 * 4 * 64 * sizeof(unsigned int), stream);

  void* args[] = {(void*)&Wh, (void*)&zx, (void*)&h0b, (void*)&h1b,
                  (void*)&out, (void*)&flags};
  hipLaunchCooperativeKernel((void*)lstm_persist, dim3(256), dim3(256),
                             args, 0, stream);
}

// Round 4
// 1941.961 us; speedup vs baseline: 4.4994x; 1.7683x over previous
//
#include <hip/hip_runtime.h>
#include <cstdint>
#include <cstddef>

// Problem constants (LSTM_62173946577315): T=256, B=128, E=1024, H=1024.
#define Tn 256
#define Bn 128
#define En 1024
#define Hn 1024
#define NG 4096   // 4*H gate rows, order [g,i,f,o]

typedef __bf16 bf16;
typedef __bf16 bf16x8 __attribute__((ext_vector_type(8)));
typedef __bf16 bf16x4 __attribute__((ext_vector_type(4)));
typedef float  f32x4  __attribute__((ext_vector_type(4)));
typedef float  f32x2  __attribute__((ext_vector_type(2)));

typedef __attribute__((address_space(1))) void gvoid;
typedef __attribute__((address_space(3))) void lvoid;

__device__ __forceinline__ float sigmoidf_(float x) {
  return 1.0f / (1.0f + __expf(-x));
}

// Unpack bf16 element j (0=low,1=high) of a u32 pair to float. j is
// compile-time under #pragma unroll.
__device__ __forceinline__ float bf16_of(unsigned w, int j) {
  unsigned short s = (j == 0) ? (unsigned short)(w & 0xffffu)
                              : (unsigned short)(w >> 16);
  return (float)__builtin_bit_cast(bf16, s);
}

// ---------------------------------------------------------------------------
// prep_w: split W_* (H x (E+H)) fp32 into Wx[4][H][E], Wh[4][H][H] bf16
// (row-major over k) and concatenate biases into bias[4096] fp32.
// ---------------------------------------------------------------------------
__global__ __launch_bounds__(256) void prep_w(
    const float* __restrict__ Wg, const float* __restrict__ Wi,
    const float* __restrict__ Wf, const float* __restrict__ Wo,
    const float* __restrict__ bg, const float* __restrict__ bi,
    const float* __restrict__ bff, const float* __restrict__ bo,
    bf16* __restrict__ Wx, bf16* __restrict__ Wh, float* __restrict__ bias)
{
  int idx = blockIdx.x * 256 + threadIdx.x;   // 0 .. 4*1024*1024-1
  int g = idx >> 20;
  int r = idx & 0xFFFFF;                      // u*1024 + k
  int u = r >> 10;
  int k = r & 1023;
  const float* Ws = (g == 0) ? Wg : (g == 1) ? Wi : (g == 2) ? Wf : Wo;
  size_t src = (size_t)u * (En + Hn) + k;
  Wx[idx] = (bf16)Ws[src];        // x-part: cols [0, E)
  Wh[idx] = (bf16)Ws[src + En];   // h-part: cols [E, E+H)
  if (idx < NG) {
    int gg = idx >> 10, uu = idx & 1023;
    const float* bs = (gg == 0) ? bg : (gg == 1) ? bi : (gg == 2) ? bff : bo;
    bias[idx] = bs[uu];
  }
}

// ---------------------------------------------------------------------------
// conv_x: embeds fp32 (T*B*E) -> bf16, vectorized x4.
// ---------------------------------------------------------------------------
__global__ __launch_bounds__(256) void conv_x(const float* __restrict__ X,
                                              bf16* __restrict__ Xb)
{
  int idx = blockIdx.x * 256 + threadIdx.x;   // per float4
  f32x4 v = ((const f32x4*)X)[idx];
  bf16x4 o;
  o[0] = (bf16)v[0]; o[1] = (bf16)v[1]; o[2] = (bf16)v[2]; o[3] = (bf16)v[3];
  ((bf16x4*)Xb)[idx] = o;
}

// ---------------------------------------------------------------------------
// zx_gemm (m97-structure): ZX[m][n] = sum_k Xb[m+128][k]*Wx[n][k] + bias[n],
// m = (t-1)*128+b for t in [1,256). M=32640, N=4096, K=1024.
// 128x128 tile, BK=32, 4 waves x (64x64 out = 4x4 16x16 frags).
// A/B staged to linear LDS via global_load_lds width=16 (per-lane global
// src, wave-uniform LDS dst + lane*16). 8 ds_read_b128 + 16 MFMA per wave
// per K-step. Measured-ladder structure (~900 TF at 4096^3).
// ---------------------------------------------------------------------------
__global__ __launch_bounds__(256) void zx_gemm(
    const bf16* __restrict__ Xb, const bf16* __restrict__ Wx,
    const float* __restrict__ bias, bf16* __restrict__ zx)
{
  const int tid  = threadIdx.x;
  const int lane = tid & 63;
  const int w    = tid >> 6;          // wave 0..3
  const int l15  = lane & 15;
  const int lq   = lane >> 4;
  const int wm   = w >> 1, wn = w & 1;

  const int n0 = blockIdx.x * 128;    // 32 n-tiles
  const int m0 = blockIdx.y * 128;    // 255 m-tiles

  __shared__ bf16 As[128 * 32];       // [row][k] 8 KB
  __shared__ bf16 Bs[128 * 32];       // [row][k] 8 KB

  const f32x4 zero4 = {0.f, 0.f, 0.f, 0.f};
  f32x4 acc[4][4];
  #pragma unroll
  for (int i = 0; i < 4; ++i)
    #pragma unroll
    for (int j = 0; j < 4; ++j) acc[i][j] = zero4;

  // Staging map: wave w owns tile rows [w*32, w*32+32). One load = 1024 B =
  // 16 rows x 64 B; lane l -> row (l>>2), col bf16 (l&3)*8. LDS dst is
  // wave-uniform; HW adds lane*16 which equals (l>>2)*64 + (l&3)*16 bytes.
  const int srow = w * 32 + (lane >> 2);
  const int scol = (lane & 3) * 8;
  const bf16* Asrc = Xb + ((size_t)(128 + m0 + srow)) * En + scol;
  const bf16* Bsrc = Wx + ((size_t)(n0 + srow)) * En + scol;
  bf16* Adst0 = &As[(w * 32 +  0) * 32];
  bf16* Adst1 = &As[(w * 32 + 16) * 32];
  bf16* Bdst0 = &Bs[(w * 32 +  0) * 32];
  bf16* Bdst1 = &Bs[(w * 32 + 16) * 32];

  for (int kc = 0; kc < En / 32; ++kc) {
    __builtin_amdgcn_global_load_lds((const gvoid*)(Asrc + kc * 32),
                                     (lvoid*)Adst0, 16, 0, 0);
    __builtin_amdgcn_global_load_lds((const gvoid*)(Asrc + (size_t)16 * En + kc * 32),
                                     (lvoid*)Adst1, 16, 0, 0);
    __builtin_amdgcn_global_load_lds((const gvoid*)(Bsrc + kc * 32),
                                     (lvoid*)Bdst0, 16, 0, 0);
    __builtin_amdgcn_global_load_lds((const gvoid*)(Bsrc + (size_t)16 * En + kc * 32),
                                     (lvoid*)Bdst1, 16, 0, 0);
    __syncthreads();

    bf16x8 a[4], b[4];
    #pragma unroll
    for (int i = 0; i < 4; ++i)
      a[i] = *(const bf16x8*)&As[(wm * 64 + i * 16 + l15) * 32 + lq * 8];
    #pragma unroll
    for (int j = 0; j < 4; ++j)
      b[j] = *(const bf16x8*)&Bs[(wn * 64 + j * 16 + l15) * 32 + lq * 8];

    #pragma unroll
    for (int i = 0; i < 4; ++i)
      #pragma unroll
      for (int j = 0; j < 4; ++j)
        acc[i][j] = __builtin_amdgcn_mfma_f32_16x16x32_bf16(a[i], b[j],
                                                            acc[i][j], 0, 0, 0);
    __syncthreads();
  }

  // Epilogue: C row = (lane>>4)*4 + reg, col = lane&15 (same convention as
  // the previously-verified kernel); fold bias, store bf16.
  #pragma unroll
  for (int i = 0; i < 4; ++i)
    #pragma unroll
    for (int j = 0; j < 4; ++j)
      #pragma unroll
      for (int r = 0; r < 4; ++r) {
        int m = m0 + wm * 64 + i * 16 + lq * 4 + r;
        int n = n0 + wn * 64 + j * 16 + l15;
        zx[(size_t)m * NG + n] = (bf16)(acc[i][j][r] + bias[n]);
      }
}

// ---------------------------------------------------------------------------
// lstm_persist: the whole 255-step scan in ONE cooperative kernel.
// Grid 256 blocks x 256 threads (1 block/CU). Block = (unit-tile ut of 16,
// batch-quarter qb of 32 rows). Wave w = gate g, holding its Wh slice
// (16 n-rows x 1024 k) in 128 VGPRs for the whole kernel.
//
// SYNC: write-once dataflow flags, NO centralized barrier.
//   Producer (end of step t): h stores are relaxed agent-scope atomic u32
//   stores (write-through to L3, the cross-XCD coherence point); per-wave
//   vmcnt(0) drain + block barrier; then tid 0 sets flag[t][qb][ut] with a
//   relaxed agent-scope store. Flag in L3 strictly after h data in L3.
//   Consumer (start of step t): all 4 waves poll the 64 flags of
//   (t-1, qb) with ONE 64-lane load + __ballot until all set, then stage h
//   via global_load_lds aux=0x11 (sc0|sc1: bypass L1/L2, read at L3).
//   WAR safety of the h ping-pong is inductive; flags write-once monotonic.
// ---------------------------------------------------------------------------
#define HS_STRIDE 1032   // 1024 + 8 bf16 pad -> 2064 B row stride

__global__ __launch_bounds__(256, 1) void lstm_persist(
    const bf16* __restrict__ Wh,    // [4][1024][1024]
    const bf16* __restrict__ zx,    // [255*128][4096] (bias folded in)
    bf16* __restrict__ hb0,         // ping [128][1024]
    bf16* __restrict__ hb1,         // pong [128][1024]
    float* __restrict__ out,        // [256][128][1024]
    unsigned int* __restrict__ flags) // [256][4][64] zero-init: [t][qb][ut]
{
  const int tid  = threadIdx.x;
  const int lane = tid & 63;
  const int g    = tid >> 6;         // wave index == gate
  const int l15  = lane & 15;
  const int lq   = lane >> 4;
  const int ut   = blockIdx.x & 63;  // unit tile (16 units)
  const int qb   = blockIdx.x >> 6;  // batch quarter (32 rows)

  __shared__ bf16  hs[32 * HS_STRIDE];   // 66,048 B
  __shared__ float zs[4][32][18];        //  9,216 B

  // --- Preload this wave's Wh slice into registers: 16 n x 1024 k ---------
  bf16x8 wfrag[32];
  {
    const bf16* wp = Wh + ((size_t)(g * Hn + ut * 16 + l15)) * Hn + lq * 8;
    #pragma unroll
    for (int ks = 0; ks < 32; ++ks)
      wfrag[ks] = *(const bf16x8*)(wp + ks * 32);
  }

  // --- Elementwise ownership: 2 ADJACENT units of one batch row -----------
  const int bl   = tid >> 3;          // 0..31 batch row within tile
  const int up0  = (tid & 7) << 1;    // 0,2,..,14 unit pair within tile
  const int brow = qb * 32 + bl;
  const int u0   = ut * 16 + up0;

  float creg[2] = {0.f, 0.f};        // c for units u0, u0+1 of row brow
  const f32x4 zero4 = {0.f, 0.f, 0.f, 0.f};

  for (int t = 1; t < Tn; ++t) {
    const bf16* hin  = ((t - 1) & 1) ? hb1 : hb0;
    bf16*       hout = (t & 1) ? hb1 : hb0;

    // --- zx prefetch: independent of h; issued before the flag wait ------
    unsigned zxw[4];
    {
      const bf16* zrow = zx + ((size_t)(t - 1) * Bn + brow) * NG + u0;
      #pragma unroll
      for (int gg = 0; gg < 4; ++gg)
        zxw[gg] = *(const unsigned*)(zrow + gg * Hn);
    }

    // --- Dataflow wait: all 64 tiles of h(t-1) for this quarter flagged --
    if (t > 1) {
      unsigned int* fp = flags + (((size_t)(t - 1)) * 4 + (size_t)qb) * 64;
      for (;;) {
        unsigned v = __hip_atomic_load(&fp[lane], __ATOMIC_RELAXED,
                                       __HIP_MEMORY_SCOPE_AGENT);
        if (__ballot(v != 0u) == ~0ULL) break;   // all 64 producers done
        __builtin_amdgcn_s_sleep(1);
      }
    }

    // --- Stage h(t-1) block tile (32 rows x 1024 k) into LDS -------------
    // 64 half-rows of 1024 B; wave g handles half-rows [g*16, g*16+16).
    // aux=0x11 (sc0|sc1): bypass L1+L2, read coherently at L3.
    #pragma unroll
    for (int j = 0; j < 16; ++j) {
      int rh   = g * 16 + j;
      int row  = rh >> 1;
      int half = rh & 1;
      const bf16* src = hin + ((size_t)(qb * 32 + row)) * Hn + half * 512 + lane * 8;
      bf16* dst = &hs[row * HS_STRIDE + half * 512];
      __builtin_amdgcn_global_load_lds((const gvoid*)src, (lvoid*)dst, 16, 0, 0x11);
    }
    __syncthreads();   // staging complete (vmcnt(0) + barrier)

    // --- z partial = h_tile @ Wh_g^T : 2 mt x 32 ks MFMAs ----------------
    f32x4 acc[2] = {zero4, zero4};
    #pragma unroll
    for (int ks = 0; ks < 32; ++ks) {
      bf16x8 a0 = *(const bf16x8*)&hs[(l15) * HS_STRIDE + ks * 32 + lq * 8];
      bf16x8 a1 = *(const bf16x8*)&hs[(16 + l15) * HS_STRIDE + ks * 32 + lq * 8];
      acc[0] = __builtin_amdgcn_mfma_f32_16x16x32_bf16(a0, wfrag[ks], acc[0], 0, 0, 0);
      acc[1] = __builtin_amdgcn_mfma_f32_16x16x32_bf16(a1, wfrag[ks], acc[1], 0, 0, 0);
    }

    // --- Gate exchange through LDS ---------------------------------------
    #pragma unroll
    for (int mt = 0; mt < 2; ++mt)
      #pragma unroll
      for (int i = 0; i < 4; ++i)
        zs[g][mt * 16 + lq * 4 + i][l15] = acc[mt][i];
    __syncthreads();

    // --- Fused elementwise: 2 adjacent cells per thread ------------------
    float hv0, hv1;
    {
      float hv[2];
      unsigned short hp[2];
      #pragma unroll
      for (int j = 0; j < 2; ++j) {
        int ul = up0 + j;
        float zg = zs[0][bl][ul] + bf16_of(zxw[0], j);
        float zi = zs[1][bl][ul] + bf16_of(zxw[1], j);
        float zf = zs[2][bl][ul] + bf16_of(zxw[2], j);
        float zo = zs[3][bl][ul] + bf16_of(zxw[3], j);
        float gv = tanhf(zg);
        float iv = sigmoidf_(zi);
        float fv = sigmoidf_(zf);
        float ov = sigmoidf_(zo);
        float cv = fv * creg[j] + iv * gv;
        creg[j] = cv;
        hv[j] = ov * tanhf(cv);
        hp[j] = __builtin_bit_cast(unsigned short, (bf16)hv[j]);
      }
      // h: relaxed agent-scope atomic store -> write-through to L3 (no fence)
      size_t off = (size_t)brow * Hn + u0;
      unsigned hpack = (unsigned)hp[0] | ((unsigned)hp[1] << 16);
      __hip_atomic_store((unsigned int*)(hout + off), hpack,
                         __ATOMIC_RELAXED, __HIP_MEMORY_SCOPE_AGENT);
      hv0 = hv[0]; hv1 = hv[1];
    }

    // --- Producer flag: h(t) of this tile is in L3 ------------------------
    asm volatile("s_waitcnt vmcnt(0)" ::: "memory");
    __syncthreads();
    if (t < Tn - 1 && tid == 0) {
      __hip_atomic_store(&flags[((size_t)t * 4 + (size_t)qb) * 64 + ut], 1u,
                         __ATOMIC_RELAXED, __HIP_MEMORY_SCOPE_AGENT);
    }

    // --- out store AFTER the flag: HBM ack latency off the critical path --
    {
      size_t off = (size_t)brow * Hn + u0;
      f32x2 ov2 = {hv0, hv1};
      __builtin_nontemporal_store(ov2, (f32x2*)(out + (size_t)t * Bn * Hn + off));
    }
  }
}

// ---------------------------------------------------------------------------
// kernel_launch
// ---------------------------------------------------------------------------
extern "C" void kernel_launch(void* const* d_in, const int* in_sizes, int n_in,
                              void* d_out, int out_size, void* d_ws, size_t ws_size,
                              hipStream_t stream) {
  const float* embeds = (const float*)d_in[0];
  const float* Wg = (const float*)d_in[1];
  const float* Wi = (const float*)d_in[2];
  const float* Wf = (const float*)d_in[3];
  const float* Wo = (const float*)d_in[4];
  const float* bg = (const float*)d_in[5];
  const float* bi = (const float*)d_in[6];
  const float* bff = (const float*)d_in[7];
  const float* bo = (const float*)d_in[8];
  float* out = (float*)d_out;

  // Workspace carve (bytes; all >=16B-aligned):
  //   Wx bf16  [4096][1024]          @ 0          (8,388,608)  [dead after
  //        zx_gemm; first 256 KB reused as the dataflow flags]
  //   Wh bf16  [4096][1024]          @ 8388608    (8,388,608)
  //   bias f32 [4096]                @ 16777216   (16,384)
  //   Xb bf16  [256][128][1024]      @ 16793600   (67,108,864)
  //   zx bf16  [32640][4096]         @ 83902464   (267,386,880)
  //   h0 bf16  [128][1024]           @ 351289344  (262,144)
  //   h1 bf16  [128][1024]           @ 351551488  (262,144)
  char* ws = (char*)d_ws;
  bf16*  Wx   = (bf16*)(ws + 0);
  bf16*  Wh   = (bf16*)(ws + 8388608);
  float* bias = (float*)(ws + 16777216);
  bf16*  Xb   = (bf16*)(ws + 16793600);
  bf16*  zx   = (bf16*)(ws + 83902464);
  bf16*  h0b  = (bf16*)(ws + 351289344);
  bf16*  h1b  = (bf16*)(ws + 351551488);
  unsigned int* flags = (unsigned int*)(ws + 0);   // aliases dead Wx region

  // out[0] = h0 = zeros; zero h ping buffer.
  hipMemsetAsync(out, 0, (size_t)Bn * Hn * sizeof(float), stream);
  hipMemsetAsync(h0b, 0, (size_t)Bn * Hn * sizeof(bf16), stream);

  prep_w<<<16384, 256, 0, stream>>>(Wg, Wi, Wf, Wo, bg, bi, bff, bo, Wx, Wh, bias);
  conv_x<<<32768, 256, 0, stream>>>(embeds, Xb);
  zx_gemm<<<dim3(32, 255), 256, 0, stream>>>(Xb, Wx, bias, zx);

  // Wx is dead now; zero the flag slots living at its base (stream-ordered
  // after zx_gemm, before the cooperative launch). [256][4][64] u32.
  hipMemsetAsync(flags, 0, (size_t)256 * 4 * 64 * sizeof(unsigned int), stream);

  void* args[] = {(void*)&Wh, (void*)&zx, (void*)&h0b, (void*)&h1b,
                  (void*)&out, (void*)&flags};
  hipLaunchCooperativeKernel((void*)lstm_persist, dim3(256), dim3(256),
                             args, 0, stream);
}

// Round 10
// 1879.835 us; speedup vs baseline: 4.6481x; 1.0330x over previous
//
#include <hip/hip_runtime.h>
#include <cstdint>
#include <cstddef>

// Problem constants (LSTM_62173946577315): T=256, B=128, E=1024, H=1024.
#define Tn 256
#define Bn 128
#define En 1024
#define Hn 1024
#define NG 4096   // 4*H gate rows, order [g,i,f,o]

typedef __bf16 bf16;
typedef __bf16 bf16x8 __attribute__((ext_vector_type(8)));
typedef __bf16 bf16x4 __attribute__((ext_vector_type(4)));
typedef float  f32x4  __attribute__((ext_vector_type(4)));
typedef float  f32x2  __attribute__((ext_vector_type(2)));

typedef __attribute__((address_space(1))) void gvoid;
typedef __attribute__((address_space(3))) void lvoid;

__device__ __forceinline__ float sigmoidf_(float x) {
  return 1.0f / (1.0f + __expf(-x));
}

// Unpack bf16 element j (0=low,1=high) of a u32 pair to float. j is
// compile-time under #pragma unroll.
__device__ __forceinline__ float bf16_of(unsigned w, int j) {
  unsigned short s = (j == 0) ? (unsigned short)(w & 0xffffu)
                              : (unsigned short)(w >> 16);
  return (float)__builtin_bit_cast(bf16, s);
}

// ---------------------------------------------------------------------------
// prep_w: split W_* (H x (E+H)) fp32 into Wx[4][H][E], Wh[4][H][H] bf16
// (row-major over k) and concatenate biases into bias[4096] fp32.
// ---------------------------------------------------------------------------
__global__ __launch_bounds__(256) void prep_w(
    const float* __restrict__ Wg, const float* __restrict__ Wi,
    const float* __restrict__ Wf, const float* __restrict__ Wo,
    const float* __restrict__ bg, const float* __restrict__ bi,
    const float* __restrict__ bff, const float* __restrict__ bo,
    bf16* __restrict__ Wx, bf16* __restrict__ Wh, float* __restrict__ bias)
{
  int idx = blockIdx.x * 256 + threadIdx.x;   // 0 .. 4*1024*1024-1
  int g = idx >> 20;
  int r = idx & 0xFFFFF;                      // u*1024 + k
  int u = r >> 10;
  int k = r & 1023;
  const float* Ws = (g == 0) ? Wg : (g == 1) ? Wi : (g == 2) ? Wf : Wo;
  size_t src = (size_t)u * (En + Hn) + k;
  Wx[idx] = (bf16)Ws[src];        // x-part: cols [0, E)
  Wh[idx] = (bf16)Ws[src + En];   // h-part: cols [E, E+H)
  if (idx < NG) {
    int gg = idx >> 10, uu = idx & 1023;
    const float* bs = (gg == 0) ? bg : (gg == 1) ? bi : (gg == 2) ? bff : bo;
    bias[idx] = bs[uu];
  }
}

// ---------------------------------------------------------------------------
// conv_x: embeds fp32 (T*B*E) -> bf16, vectorized x4.
// ---------------------------------------------------------------------------
__global__ __launch_bounds__(256) void conv_x(const float* __restrict__ X,
                                              bf16* __restrict__ Xb)
{
  int idx = blockIdx.x * 256 + threadIdx.x;   // per float4
  f32x4 v = ((const f32x4*)X)[idx];
  bf16x4 o;
  o[0] = (bf16)v[0]; o[1] = (bf16)v[1]; o[2] = (bf16)v[2]; o[3] = (bf16)v[3];
  ((bf16x4*)Xb)[idx] = o;
}

// ---------------------------------------------------------------------------
// zx_gemm (m97-structure): ZX[m][n] = sum_k Xb[m+128][k]*Wx[n][k] + bias[n],
// m = (t-1)*128+b for t in [1,256). M=32640, N=4096, K=1024.
// 128x128 tile, BK=32, 4 waves x (64x64 out = 4x4 16x16 frags).
// ---------------------------------------------------------------------------
__global__ __launch_bounds__(256) void zx_gemm(
    const bf16* __restrict__ Xb, const bf16* __restrict__ Wx,
    const float* __restrict__ bias, bf16* __restrict__ zx)
{
  const int tid  = threadIdx.x;
  const int lane = tid & 63;
  const int w    = tid >> 6;          // wave 0..3
  const int l15  = lane & 15;
  const int lq   = lane >> 4;
  const int wm   = w >> 1, wn = w & 1;

  const int n0 = blockIdx.x * 128;    // 32 n-tiles
  const int m0 = blockIdx.y * 128;    // 255 m-tiles

  __shared__ bf16 As[128 * 32];       // [row][k] 8 KB
  __shared__ bf16 Bs[128 * 32];       // [row][k] 8 KB

  const f32x4 zero4 = {0.f, 0.f, 0.f, 0.f};
  f32x4 acc[4][4];
  #pragma unroll
  for (int i = 0; i < 4; ++i)
    #pragma unroll
    for (int j = 0; j < 4; ++j) acc[i][j] = zero4;

  const int srow = w * 32 + (lane >> 2);
  const int scol = (lane & 3) * 8;
  const bf16* Asrc = Xb + ((size_t)(128 + m0 + srow)) * En + scol;
  const bf16* Bsrc = Wx + ((size_t)(n0 + srow)) * En + scol;
  bf16* Adst0 = &As[(w * 32 +  0) * 32];
  bf16* Adst1 = &As[(w * 32 + 16) * 32];
  bf16* Bdst0 = &Bs[(w * 32 +  0) * 32];
  bf16* Bdst1 = &Bs[(w * 32 + 16) * 32];

  for (int kc = 0; kc < En / 32; ++kc) {
    __builtin_amdgcn_global_load_lds((const gvoid*)(Asrc + kc * 32),
                                     (lvoid*)Adst0, 16, 0, 0);
    __builtin_amdgcn_global_load_lds((const gvoid*)(Asrc + (size_t)16 * En + kc * 32),
                                     (lvoid*)Adst1, 16, 0, 0);
    __builtin_amdgcn_global_load_lds((const gvoid*)(Bsrc + kc * 32),
                                     (lvoid*)Bdst0, 16, 0, 0);
    __builtin_amdgcn_global_load_lds((const gvoid*)(Bsrc + (size_t)16 * En + kc * 32),
                                     (lvoid*)Bdst1, 16, 0, 0);
    __syncthreads();

    bf16x8 a[4], b[4];
    #pragma unroll
    for (int i = 0; i < 4; ++i)
      a[i] = *(const bf16x8*)&As[(wm * 64 + i * 16 + l15) * 32 + lq * 8];
    #pragma unroll
    for (int j = 0; j < 4; ++j)
      b[j] = *(const bf16x8*)&Bs[(wn * 64 + j * 16 + l15) * 32 + lq * 8];

    #pragma unroll
    for (int i = 0; i < 4; ++i)
      #pragma unroll
      for (int j = 0; j < 4; ++j)
        acc[i][j] = __builtin_amdgcn_mfma_f32_16x16x32_bf16(a[i], b[j],
                                                            acc[i][j], 0, 0, 0);
    __syncthreads();
  }

  #pragma unroll
  for (int i = 0; i < 4; ++i)
    #pragma unroll
    for (int j = 0; j < 4; ++j)
      #pragma unroll
      for (int r = 0; r < 4; ++r) {
        int m = m0 + wm * 64 + i * 16 + lq * 4 + r;
        int n = n0 + wn * 64 + j * 16 + l15;
        zx[(size_t)m * NG + n] = (bf16)(acc[i][j][r] + bias[n]);
      }
}

// ---------------------------------------------------------------------------
// lstm_persist: 255-step scan in ONE cooperative kernel.
// Grid 256 blocks x 256 threads (1 block/CU). Block = (ut of 16 units,
// qb of 32 batch rows).
//
// WAVE DECOMPOSITION: waves split by K-QUARTER, not by gate.
// Wave kq holds Wh fragments for ALL 4 gates over k in [256*kq, 256*kq+256)
// (4 gates x 8 k-slices = 32 bf16x8 = 128 VGPR) and computes partial z for
// all 4 gates. Each A-fragment pair feeds 8 MFMAs instead of 2 -> LDS
// A-read volume drops 4x (256 KB -> 64 KB per CU per step). Cross-wave
// k-reduction rides the zs exchange: zs[kq][gate][row][col].
//
// SYNC (verified round 3/4): write-once dataflow flags; h stores relaxed
// agent-scope atomic u32 (write-through to L3); consumers poll 64 flags
// with one 64-lane load + __ballot; h staged via global_load_lds aux=0x11
// (sc0|sc1). WAR safety of ping-pong is inductive.
// ---------------------------------------------------------------------------
#define HS_STRIDE 1032   // 1024 + 8 bf16 pad -> 2064 B row stride

__global__ __launch_bounds__(256, 1) void lstm_persist(
    const bf16* __restrict__ Wh,    // [4][1024][1024]
    const bf16* __restrict__ zx,    // [255*128][4096] (bias folded in)
    bf16* __restrict__ hb0,         // ping [128][1024]
    bf16* __restrict__ hb1,         // pong [128][1024]
    float* __restrict__ out,        // [256][128][1024]
    unsigned int* __restrict__ flags) // [256][4][64] zero-init: [t][qb][ut]
{
  const int tid  = threadIdx.x;
  const int lane = tid & 63;
  const int kq   = tid >> 6;         // wave index == k-quarter
  const int l15  = lane & 15;
  const int lq   = lane >> 4;
  const int ut   = blockIdx.x & 63;  // unit tile (16 units)
  const int qb   = blockIdx.x >> 6;  // batch quarter (32 rows)

  __shared__ bf16  hs[32 * HS_STRIDE];   // 66,048 B
  __shared__ float zs[4][4][32][18];     // 36,864 B  [kq][gate][row][col]

  // --- Preload Wh fragments: ALL 4 gates x this wave's k-quarter ----------
  // wfrag[g][ks] covers Wh[g*1024 + ut*16 + l15][kq*256 + ks*32 + lq*8 ..+8]
  bf16x8 wfrag[4][8];
  #pragma unroll
  for (int g = 0; g < 4; ++g) {
    const bf16* wp = Wh + ((size_t)(g * Hn + ut * 16 + l15)) * Hn
                        + kq * 256 + lq * 8;
    #pragma unroll
    for (int ks = 0; ks < 8; ++ks)
      wfrag[g][ks] = *(const bf16x8*)(wp + ks * 32);
  }

  // --- Elementwise ownership: 2 ADJACENT units of one batch row -----------
  const int bl   = tid >> 3;          // 0..31 batch row within tile
  const int up0  = (tid & 7) << 1;    // 0,2,..,14 unit pair within tile
  const int brow = qb * 32 + bl;
  const int u0   = ut * 16 + up0;

  float creg[2] = {0.f, 0.f};        // c for units u0, u0+1 of row brow
  const f32x4 zero4 = {0.f, 0.f, 0.f, 0.f};

  for (int t = 1; t < Tn; ++t) {
    const bf16* hin  = ((t - 1) & 1) ? hb1 : hb0;
    bf16*       hout = (t & 1) ? hb1 : hb0;

    // --- zx prefetch: independent of h; issued before the flag wait ------
    unsigned zxw[4];
    {
      const bf16* zrow = zx + ((size_t)(t - 1) * Bn + brow) * NG + u0;
      #pragma unroll
      for (int gg = 0; gg < 4; ++gg)
        zxw[gg] = *(const unsigned*)(zrow + gg * Hn);
    }

    // --- Dataflow wait: all 64 tiles of h(t-1) for this quarter flagged --
    if (t > 1) {
      unsigned int* fp = flags + (((size_t)(t - 1)) * 4 + (size_t)qb) * 64;
      for (;;) {
        unsigned v = __hip_atomic_load(&fp[lane], __ATOMIC_RELAXED,
                                       __HIP_MEMORY_SCOPE_AGENT);
        if (__ballot(v != 0u) == ~0ULL) break;   // all 64 producers done
        __builtin_amdgcn_s_sleep(1);
      }
    }

    // --- Stage h(t-1) block tile (32 rows x 1024 k) into LDS -------------
    // 64 half-rows of 1024 B; wave kq handles half-rows [kq*16, kq*16+16).
    // aux=0x11 (sc0|sc1): bypass L1+L2, read coherently at L3.
    #pragma unroll
    for (int j = 0; j < 16; ++j) {
      int rh   = kq * 16 + j;
      int row  = rh >> 1;
      int half = rh & 1;
      const bf16* src = hin + ((size_t)(qb * 32 + row)) * Hn + half * 512 + lane * 8;
      bf16* dst = &hs[row * HS_STRIDE + half * 512];
      __builtin_amdgcn_global_load_lds((const gvoid*)src, (lvoid*)dst, 16, 0, 0x11);
    }
    __syncthreads();   // staging complete (vmcnt(0) + barrier)

    // --- partial z (all gates) over this wave's k-quarter ----------------
    // 8 ks x {2 ds_read_b128 -> 8 MFMA}: A-frags shared by all 4 gates.
    f32x4 acc[2][4];
    #pragma unroll
    for (int mt = 0; mt < 2; ++mt)
      #pragma unroll
      for (int g = 0; g < 4; ++g) acc[mt][g] = zero4;

    #pragma unroll
    for (int ks = 0; ks < 8; ++ks) {
      bf16x8 a0 = *(const bf16x8*)&hs[(l15) * HS_STRIDE + kq * 256 + ks * 32 + lq * 8];
      bf16x8 a1 = *(const bf16x8*)&hs[(16 + l15) * HS_STRIDE + kq * 256 + ks * 32 + lq * 8];
      #pragma unroll
      for (int g = 0; g < 4; ++g) {
        acc[0][g] = __builtin_amdgcn_mfma_f32_16x16x32_bf16(a0, wfrag[g][ks],
                                                            acc[0][g], 0, 0, 0);
        acc[1][g] = __builtin_amdgcn_mfma_f32_16x16x32_bf16(a1, wfrag[g][ks],
                                                            acc[1][g], 0, 0, 0);
      }
    }

    // --- k-partial exchange through LDS ----------------------------------
    #pragma unroll
    for (int g = 0; g < 4; ++g)
      #pragma unroll
      for (int mt = 0; mt < 2; ++mt)
        #pragma unroll
        for (int i = 0; i < 4; ++i)
          zs[kq][g][mt * 16 + lq * 4 + i][l15] = acc[mt][g][i];
    __syncthreads();

    // --- Fused elementwise: 2 adjacent cells; sum the 4 k-partials -------
    float hv0, hv1;
    {
      float zsum[4][2];
      #pragma unroll
      for (int g = 0; g < 4; ++g) { zsum[g][0] = 0.f; zsum[g][1] = 0.f; }
      #pragma unroll
      for (int kk = 0; kk < 4; ++kk)
        #pragma unroll
        for (int g = 0; g < 4; ++g) {
          f32x2 v = *(const f32x2*)&zs[kk][g][bl][up0];
          zsum[g][0] += v[0];
          zsum[g][1] += v[1];
        }

      float hv[2];
      unsigned short hp[2];
      #pragma unroll
      for (int j = 0; j < 2; ++j) {
        float zg = zsum[0][j] + bf16_of(zxw[0], j);
        float zi = zsum[1][j] + bf16_of(zxw[1], j);
        float zf = zsum[2][j] + bf16_of(zxw[2], j);
        float zo = zsum[3][j] + bf16_of(zxw[3], j);
        float gv = tanhf(zg);
        float iv = sigmoidf_(zi);
        float fv = sigmoidf_(zf);
        float ov = sigmoidf_(zo);
        float cv = fv * creg[j] + iv * gv;
        creg[j] = cv;
        hv[j] = ov * tanhf(cv);
        hp[j] = __builtin_bit_cast(unsigned short, (bf16)hv[j]);
      }
      // h: relaxed agent-scope atomic store -> write-through to L3 (no fence)
      size_t off = (size_t)brow * Hn + u0;
      unsigned hpack = (unsigned)hp[0] | ((unsigned)hp[1] << 16);
      __hip_atomic_store((unsigned int*)(hout + off), hpack,
                         __ATOMIC_RELAXED, __HIP_MEMORY_SCOPE_AGENT);
      hv0 = hv[0]; hv1 = hv[1];
    }

    // --- Producer flag: h(t) of this tile is in L3 ------------------------
    asm volatile("s_waitcnt vmcnt(0)" ::: "memory");
    __syncthreads();
    if (t < Tn - 1 && tid == 0) {
      __hip_atomic_store(&flags[((size_t)t * 4 + (size_t)qb) * 64 + ut], 1u,
                         __ATOMIC_RELAXED, __HIP_MEMORY_SCOPE_AGENT);
    }

    // --- out store AFTER the flag: HBM ack latency off the critical path --
    {
      size_t off = (size_t)brow * Hn + u0;
      f32x2 ov2 = {hv0, hv1};
      __builtin_nontemporal_store(ov2, (f32x2*)(out + (size_t)t * Bn * Hn + off));
    }
  }
}

// ---------------------------------------------------------------------------
// kernel_launch
// ---------------------------------------------------------------------------
extern "C" void kernel_launch(void* const* d_in, const int* in_sizes, int n_in,
                              void* d_out, int out_size, void* d_ws, size_t ws_size,
                              hipStream_t stream) {
  const float* embeds = (const float*)d_in[0];
  const float* Wg = (const float*)d_in[1];
  const float* Wi = (const float*)d_in[2];
  const float* Wf = (const float*)d_in[3];
  const float* Wo = (const float*)d_in[4];
  const float* bg = (const float*)d_in[5];
  const float* bi = (const float*)d_in[6];
  const float* bff = (const float*)d_in[7];
  const float* bo = (const float*)d_in[8];
  float* out = (float*)d_out;

  // Workspace carve (bytes; all >=16B-aligned):
  //   Wx bf16  [4096][1024]          @ 0          (8,388,608)  [dead after
  //        zx_gemm; first 256 KB reused as the dataflow flags]
  //   Wh bf16  [4096][1024]          @ 8388608    (8,388,608)
  //   bias f32 [4096]                @ 16777216   (16,384)
  //   Xb bf16  [256][128][1024]      @ 16793600   (67,108,864)
  //   zx bf16  [32640][4096]         @ 83902464   (267,386,880)
  //   h0 bf16  [128][1024]           @ 351289344  (262,144)
  //   h1 bf16  [128][1024]           @ 351551488  (262,144)
  char* ws = (char*)d_ws;
  bf16*  Wx   = (bf16*)(ws + 0);
  bf16*  Wh   = (bf16*)(ws + 8388608);
  float* bias = (float*)(ws + 16777216);
  bf16*  Xb   = (bf16*)(ws + 16793600);
  bf16*  zx   = (bf16*)(ws + 83902464);
  bf16*  h0b  = (bf16*)(ws + 351289344);
  bf16*  h1b  = (bf16*)(ws + 351551488);
  unsigned int* flags = (unsigned int*)(ws + 0);   // aliases dead Wx region

  // out[0] = h0 = zeros; zero h ping buffer.
  hipMemsetAsync(out, 0, (size_t)Bn * Hn * sizeof(float), stream);
  hipMemsetAsync(h0b, 0, (size_t)Bn * Hn * sizeof(bf16), stream);

  prep_w<<<16384, 256, 0, stream>>>(Wg, Wi, Wf, Wo, bg, bi, bff, bo, Wx, Wh, bias);
  conv_x<<<32768, 256, 0, stream>>>(embeds, Xb);
  zx_gemm<<<dim3(32, 255), 256, 0, stream>>>(Xb, Wx, bias, zx);

  // Wx is dead now; zero the flag slots living at its base (stream-ordered
  // after zx_gemm, before the cooperative launch). [256][4][64] u32.
  hipMemsetAsync(flags, 0, (size_t)256 * 4 * 64 * sizeof(unsigned int), stream);

  void* args[] = {(void*)&Wh, (void*)&zx, (void*)&h0b, (void*)&h1b,
                  (void*)&out, (void*)&flags};
  hipLaunchCooperativeKernel((void*)lstm_persist, dim3(256), dim3(256),
                             args, 0, stream);
}